// Round 4
// baseline (117.756 us; speedup 1.0000x reference)
//
#include <hip/hip_runtime.h>

#define NN 8
#define HH 512
#define WW 512
#define CC 3
#define KK 5
#define PADP 2
#define BLK 256

// 4-byte-aligned vector types: input/weight bases are only dword-aligned
// (12B / 100B strides). CDNA multi-dword global loads need only dword align.
typedef float float4a __attribute__((ext_vector_type(4), aligned(4)));
typedef float float2a __attribute__((ext_vector_type(2), aligned(4)));

__global__ __launch_bounds__(256, 8) void conv_local_kernel(
    const float* __restrict__ in,   // (N,H,W,C)
    const float* __restrict__ wt,   // (N,H,W,25)
    float* __restrict__ out)        // (N,H,W,C)
{
    const int tid  = threadIdx.x;
    const int blk  = blockIdx.x;           // 0..8191
    const int wseg = blk & 1;
    const int h    = (blk >> 1) & (HH - 1);   // block-uniform row
    const int n    = blk >> 10;
    const int w    = wseg * BLK + tid;
    const int gid  = (n * HH + h) * WW + w;

    const float* wp  = wt + (size_t)gid * (KK * KK);
    const float* inb = in + (size_t)n * (HH * WW * CC);

    float acc0 = 0.f, acc1 = 0.f, acc2 = 0.f;

    const bool interior = (h >= PADP) && (h < HH - PADP) &&
                          (w >= PADP) && (w < WW - PADP);

    if (interior) {
        // fast path: fully vectorized, no bounds checks
        const float* ib = inb + ((h - PADP) * WW + (w - PADP)) * CC;
#pragma unroll
        for (int dh = 0; dh < KK; ++dh) {
            const float* wrow = wp + dh * KK;         // 5 weights for this row
            float4a w4 = *(const float4a*)wrow;
            float   w5 = wrow[4];
            const float* rp = ib + dh * (WW * CC);    // 15-float input window
            float4a r0 = *(const float4a*)(rp);       // f0..f3
            float4a r1 = *(const float4a*)(rp + 4);   // f4..f7
            float4a r2 = *(const float4a*)(rp + 8);   // f8..f11
            float4a r3 = *(const float4a*)(rp + 11);  // f11..f14 (overlap keeps last load in-bounds)
            // tap dw uses floats [3*dw .. 3*dw+2]
            acc0 = fmaf(r0[0], w4[0], acc0);
            acc1 = fmaf(r0[1], w4[0], acc1);
            acc2 = fmaf(r0[2], w4[0], acc2);
            acc0 = fmaf(r0[3], w4[1], acc0);
            acc1 = fmaf(r1[0], w4[1], acc1);
            acc2 = fmaf(r1[1], w4[1], acc2);
            acc0 = fmaf(r1[2], w4[2], acc0);
            acc1 = fmaf(r1[3], w4[2], acc1);
            acc2 = fmaf(r2[0], w4[2], acc2);
            acc0 = fmaf(r2[1], w4[3], acc0);
            acc1 = fmaf(r2[2], w4[3], acc1);
            acc2 = fmaf(r2[3], w4[3], acc2);
            acc0 = fmaf(r3[1], w5, acc0);
            acc1 = fmaf(r3[2], w5, acc1);
            acc2 = fmaf(r3[3], w5, acc2);
        }
    } else {
        // slow path: border pixels, per-tap predication (round-1 code)
        float wreg[KK * KK];
#pragma unroll
        for (int k = 0; k < KK * KK; ++k) wreg[k] = wp[k];
#pragma unroll
        for (int dh = 0; dh < KK; ++dh) {
            const int ih = h + dh - PADP;
            const bool rok = ((unsigned)ih < (unsigned)HH);
#pragma unroll
            for (int dw = 0; dw < KK; ++dw) {
                const int iw = w + dw - PADP;
                const bool ok = rok && ((unsigned)iw < (unsigned)WW);
                const float* p = inb + ((size_t)(ih * WW + iw)) * CC;
                float v0 = ok ? p[0] : 0.f;
                float v1 = ok ? p[1] : 0.f;
                float v2 = ok ? p[2] : 0.f;
                const float wv = wreg[dh * KK + dw];
                acc0 = fmaf(v0, wv, acc0);
                acc1 = fmaf(v1, wv, acc1);
                acc2 = fmaf(v2, wv, acc2);
            }
        }
    }

    float* op = out + (size_t)gid * CC;
    float2a o01;
    o01[0] = acc0;
    o01[1] = acc1;
    *(float2a*)op = o01;
    op[2] = acc2;
}

extern "C" void kernel_launch(void* const* d_in, const int* in_sizes, int n_in,
                              void* d_out, int out_size, void* d_ws, size_t ws_size,
                              hipStream_t stream) {
    const float* in = (const float*)d_in[0];   // (8,512,512,3) f32
    const float* wt = (const float*)d_in[1];   // (8,512,512,25) f32
    float* out = (float*)d_out;                // (8,512,512,3) f32

    const int grid = NN * HH * (WW / BLK);     // 8192 blocks
    conv_local_kernel<<<grid, BLK, 0, stream>>>(in, wt, out);
}

// Round 5
// 85.937 us; speedup vs baseline: 1.3703x; 1.3703x over previous
//
#include <hip/hip_runtime.h>

#define NN 8
#define HH 512
#define WW 512
#define CC 3
#define KK 5
#define PADP 2

__global__ __launch_bounds__(256) void conv_local_kernel(
    const float* __restrict__ in,   // (N,H,W,C)
    const float* __restrict__ wt,   // (N,H,W,25)
    float* __restrict__ out)        // (N,H,W,C)
{
    // Bijective XCD-contiguous swizzle (grid = 8192, 8192 % 8 == 0):
    // HW round-robins consecutive blockIdx across the 8 XCDs; remap so each
    // XCD processes one contiguous 1024-block (26 MB weight) range linearly.
    const int b = ((blockIdx.x & 7) << 10) | (blockIdx.x >> 3);

    const int gid = b * 256 + (int)threadIdx.x;   // pixel id in [0, N*H*W)
    const int w = gid & (WW - 1);
    const int h = (gid >> 9) & (HH - 1);
    const int n = gid >> 18;

    // --- load the 25 per-pixel weights into registers (issued first: bulk stream) ---
    const float* wp = wt + (size_t)gid * (KK * KK);
    float wreg[KK * KK];
#pragma unroll
    for (int k = 0; k < KK * KK; ++k) wreg[k] = wp[k];

    // --- 5x5 tap loop, 3 channels accumulated in registers ---
    float acc0 = 0.f, acc1 = 0.f, acc2 = 0.f;
    const float* inp = in + (size_t)n * (HH * WW * CC);
#pragma unroll
    for (int dh = 0; dh < KK; ++dh) {
        const int ih = h + dh - PADP;
        const bool rok = ((unsigned)ih < (unsigned)HH);
#pragma unroll
        for (int dw = 0; dw < KK; ++dw) {
            const int iw = w + dw - PADP;
            const bool ok = rok && ((unsigned)iw < (unsigned)WW);
            const float* p = inp + ((size_t)(ih * WW + iw)) * CC;
            float v0 = ok ? p[0] : 0.f;
            float v1 = ok ? p[1] : 0.f;
            float v2 = ok ? p[2] : 0.f;
            const float wv = wreg[dh * KK + dw];
            acc0 = fmaf(v0, wv, acc0);
            acc1 = fmaf(v1, wv, acc1);
            acc2 = fmaf(v2, wv, acc2);
        }
    }

    float* op = out + (size_t)gid * CC;
    op[0] = acc0;
    op[1] = acc1;
    op[2] = acc2;
}

extern "C" void kernel_launch(void* const* d_in, const int* in_sizes, int n_in,
                              void* d_out, int out_size, void* d_ws, size_t ws_size,
                              hipStream_t stream) {
    const float* in = (const float*)d_in[0];   // (8,512,512,3) f32
    const float* wt = (const float*)d_in[1];   // (8,512,512,25) f32
    float* out = (float*)d_out;                // (8,512,512,3) f32

    const int total_pixels = NN * HH * WW;     // 2,097,152
    const int block = 256;
    const int grid = total_pixels / block;     // 8192
    conv_local_kernel<<<grid, block, 0, stream>>>(in, wt, out);
}

// Round 6
// 64.195 us; speedup vs baseline: 1.8344x; 1.3387x over previous
//
#include <hip/hip_runtime.h>

#define NN 8
#define HH 512
#define WW 512
#define CC 3
#define KK 5
#define PADP 2
#define BLK 64                     // 1 wave per block, no barriers
#define WROW 216                   // staged floats per input row (68 px * 3, padded to 72*3)
#define NBLOCKS (NN * HH * WW / BLK)   // 32768

typedef float float4v __attribute__((ext_vector_type(4)));

__global__ __launch_bounds__(64, 4) void conv_local_kernel(
    const float* __restrict__ in,   // (N,H,W,C)
    const float* __restrict__ wt,   // (N,H,W,25)
    float* __restrict__ out)        // (N,H,W,C)
{
    __shared__ float w_lds[BLK * KK * KK];   // 1600 f = 6.4 KB
    __shared__ float in_lds[KK * WROW];      // 1080 f = 4.3 KB

    const int lane = threadIdx.x;            // 0..63
    // bijective XCD-contiguous swizzle: 32768 blocks, 4096 per XCD
    const int b = ((blockIdx.x & 7) << 12) | (blockIdx.x >> 3);

    const int w0 = (b & 7) << 6;             // 0,64,...,448 (block-uniform)
    const int h  = (b >> 3) & (HH - 1);      // block-uniform
    const int n  = b >> 12;
    const long pix0 = (long)b * BLK;

    // ---- stage weights: 1600 dwords, aligned dwordx4, fully coalesced ----
    const float*   wsrc  = wt + pix0 * (KK * KK);          // 6400B-aligned
    const float4v* wsrc4 = (const float4v*)wsrc;
    float4v*       wl4   = (float4v*)w_lds;
#pragma unroll
    for (int it = 0; it < 6; ++it)
        wl4[it * BLK + lane] = wsrc4[it * BLK + lane];     // 384 float4 = 1536 f
    w_lds[1536 + lane] = wsrc[1536 + lane];                // tail 64 f

    // ---- stage input: 5 rows x 204 floats, coalesced b32, uniform bounds ----
    const float* inb = in + (size_t)n * (HH * WW * CC);
    const int fi_lo = (w0 == 0) ? 6 : 0;                  // gw >= 0
    const int fi_hi = (w0 == WW - BLK) ? 198 : 204;       // gw < 512
#pragma unroll
    for (int r = 0; r < KK; ++r) {
        const int gh = h + r - PADP;
        const bool rowok = ((unsigned)gh < (unsigned)HH);
        const long base = ((long)gh * WW + (w0 - PADP)) * CC;   // float index of fi=0
#pragma unroll
        for (int c64 = 0; c64 < 4; ++c64) {
            const int fi = c64 * BLK + lane;
            if (fi < 204) {
                float v = 0.f;
                if (rowok && fi >= fi_lo && fi < fi_hi) v = inb[base + fi];
                in_lds[r * WROW + fi] = v;
            }
        }
    }
    // single wave: no __syncthreads needed (lgkmcnt dependency only)

    // ---- compute: 25 taps x 3 channels, LDS base + immediate offsets ----
    float acc0 = 0.f, acc1 = 0.f, acc2 = 0.f;
    const float* wp = &w_lds[lane * (KK * KK)];
    const float* ip = &in_lds[lane * CC];
#pragma unroll
    for (int dh = 0; dh < KK; ++dh) {
#pragma unroll
        for (int dw = 0; dw < KK; ++dw) {
            const float wv = wp[dh * KK + dw];
            const int o = dh * WROW + dw * CC;
            acc0 = fmaf(ip[o + 0], wv, acc0);
            acc1 = fmaf(ip[o + 1], wv, acc1);
            acc2 = fmaf(ip[o + 2], wv, acc2);
        }
    }

    float* op = out + pix0 * CC + lane * CC;
    op[0] = acc0;
    op[1] = acc1;
    op[2] = acc2;
}

extern "C" void kernel_launch(void* const* d_in, const int* in_sizes, int n_in,
                              void* d_out, int out_size, void* d_ws, size_t ws_size,
                              hipStream_t stream) {
    const float* in = (const float*)d_in[0];   // (8,512,512,3) f32
    const float* wt = (const float*)d_in[1];   // (8,512,512,25) f32
    float* out = (float*)d_out;                // (8,512,512,3) f32

    conv_local_kernel<<<NBLOCKS, BLK, 0, stream>>>(in, wt, out);
}

// Round 7
// 58.954 us; speedup vs baseline: 1.9974x; 1.0889x over previous
//
#include <hip/hip_runtime.h>

#define NN 8
#define HH 512
#define WW 512
#define CC 3
#define KK 5
#define PADP 2
#define WROWF (WW * CC)                 // 1536 floats per image row
#define NBLOCKS (NN * HH * WW / 128)    // 16384 blocks: 64 px wide x 2 rows

typedef float f4a __attribute__((ext_vector_type(4), aligned(4)));

struct Row { f4a L0, L1, L2, L3; };     // 15-float window f0..f14 (L3 overlaps at f11)

__device__ __forceinline__ void load_row(const float* rb, Row& r) {
    r.L0 = *(const f4a*)(rb);
    r.L1 = *(const f4a*)(rb + 4);
    r.L2 = *(const f4a*)(rb + 8);
    r.L3 = *(const f4a*)(rb + 11);
}

// taps: dw uses floats [3*dw .. 3*dw+2] of the window
__device__ __forceinline__ void fma_row(const Row& r, const float* wp,
                                        float& a0, float& a1, float& a2) {
    const float w0 = wp[0], w1 = wp[1], w2 = wp[2], w3 = wp[3], w4 = wp[4];
    a0 = fmaf(r.L0[0], w0, a0); a1 = fmaf(r.L0[1], w0, a1); a2 = fmaf(r.L0[2], w0, a2);
    a0 = fmaf(r.L0[3], w1, a0); a1 = fmaf(r.L1[0], w1, a1); a2 = fmaf(r.L1[1], w1, a2);
    a0 = fmaf(r.L1[2], w2, a0); a1 = fmaf(r.L1[3], w2, a1); a2 = fmaf(r.L2[0], w2, a2);
    a0 = fmaf(r.L2[1], w3, a0); a1 = fmaf(r.L2[2], w3, a1); a2 = fmaf(r.L2[3], w3, a2);
    a0 = fmaf(r.L3[1], w4, a0); a1 = fmaf(r.L3[2], w4, a1); a2 = fmaf(r.L3[3], w4, a2);
}

#define GLDS16(gp, lp) __builtin_amdgcn_global_load_lds( \
    (const __attribute__((address_space(1))) void*)(gp), \
    (__attribute__((address_space(3))) void*)(lp), 16, 0, 0)
#define GLDS4(gp, lp) __builtin_amdgcn_global_load_lds( \
    (const __attribute__((address_space(1))) void*)(gp), \
    (__attribute__((address_space(3))) void*)(lp), 4, 0, 0)

__global__ __launch_bounds__(64, 3) void conv_local_kernel(
    const float* __restrict__ in,   // (N,H,W,C)
    const float* __restrict__ wt,   // (N,H,W,25)
    float* __restrict__ out)        // (N,H,W,C)
{
    __shared__ float w_lds[2 * 64 * KK * KK];   // 3200 f = 12.8 KB

    const int lane = threadIdx.x;
    // bijective XCD swizzle: 16384 = 8 x 2048; each XCD streams one image linearly
    const int b    = ((blockIdx.x & 7) << 11) | (blockIdx.x >> 3);
    const int wseg = b & 7;
    const int hp   = (b >> 3) & 255;
    const int n    = b >> 11;
    const int w0   = wseg << 6;                 // 0..448
    const int h0   = hp << 1;                   // 0..510

    const long pix0 = ((long)(n * HH + h0)) * WW + w0;   // row h0, col w0
    const long pix1 = pix0 + WW;                          // row h0+1
    const float* inb = in + (size_t)n * (HH * WW * CC);

    // ---- stage weights for both output rows: 2 x 1600 dwords, async global->LDS ----
    {
        const char* s0 = (const char*)(wt + pix0 * (KK * KK));
        const char* s1 = (const char*)(wt + pix1 * (KK * KK));
#pragma unroll
        for (int it = 0; it < 6; ++it)
            GLDS16(s0 + it * 1024 + lane * 16, &w_lds[it * 256]);
        GLDS4(s0 + 6144 + lane * 4, &w_lds[1536]);
#pragma unroll
        for (int it = 0; it < 6; ++it)
            GLDS16(s1 + it * 1024 + lane * 16, &w_lds[1600 + it * 256]);
        GLDS4(s1 + 6144 + lane * 4, &w_lds[1600 + 1536]);
    }

    const float* wp0 = &w_lds[lane * (KK * KK)];          // px row h0 weights
    const float* wp1 = &w_lds[1600 + lane * (KK * KK)];   // px row h0+1 weights

    const bool fast = (w0 != 0) && (w0 != WW - 64) && (h0 >= PADP) && (h0 <= HH - 4);

    if (fast) {
        // 6 input rows gh = h0-2 .. h0+3; A/B register double-buffer, no LDS for input
        const float* rb = inb + ((long)(h0 - PADP) * WW + (w0 + lane - PADP)) * CC;
        Row A, B;
        load_row(rb, A);
        load_row(rb + WROWF, B);
        // drain global_load_lds before ds_reads (dependency not register-tracked)
        asm volatile("s_waitcnt vmcnt(0)" ::: "memory");

        float a0 = 0.f, a1 = 0.f, a2 = 0.f;   // acc for px (h0, w)
        float c0 = 0.f, c1 = 0.f, c2 = 0.f;   // acc for px (h0+1, w)

        // j=0: row h0-2 -> px0 dh=0
        fma_row(A, wp0 + 0, a0, a1, a2);
        load_row(rb + 2 * WROWF, A);
        // j=1: row h0-1 -> px0 dh=1, px1 dh=0
        fma_row(B, wp0 + 5, a0, a1, a2);
        fma_row(B, wp1 + 0, c0, c1, c2);
        load_row(rb + 3 * WROWF, B);
        // j=2
        fma_row(A, wp0 + 10, a0, a1, a2);
        fma_row(A, wp1 + 5, c0, c1, c2);
        load_row(rb + 4 * WROWF, A);
        // j=3
        fma_row(B, wp0 + 15, a0, a1, a2);
        fma_row(B, wp1 + 10, c0, c1, c2);
        load_row(rb + 5 * WROWF, B);
        // j=4
        fma_row(A, wp0 + 20, a0, a1, a2);
        fma_row(A, wp1 + 15, c0, c1, c2);
        // j=5: row h0+3 -> px1 dh=4
        fma_row(B, wp1 + 20, c0, c1, c2);

        float* o0 = out + (pix0 + lane) * CC;
        o0[0] = a0; o0[1] = a1; o0[2] = a2;
        float* o1 = out + (pix1 + lane) * CC;
        o1[0] = c0; o1[1] = c1; o1[2] = c2;
    } else {
        asm volatile("s_waitcnt vmcnt(0)" ::: "memory");
        // border blocks: predicated scalar path (proven in R1), weights from LDS
#pragma unroll
        for (int px = 0; px < 2; ++px) {
            const int hh = h0 + px;
            const int w  = w0 + lane;
            const float* wp = px ? wp1 : wp0;
            float a0 = 0.f, a1 = 0.f, a2 = 0.f;
#pragma unroll
            for (int dh = 0; dh < KK; ++dh) {
                const int ih = hh + dh - PADP;
                const bool rok = ((unsigned)ih < (unsigned)HH);
#pragma unroll
                for (int dw = 0; dw < KK; ++dw) {
                    const int iw = w + dw - PADP;
                    const bool ok = rok && ((unsigned)iw < (unsigned)WW);
                    const float* p = inb + ((long)(ih * WW + iw)) * CC;
                    float v0 = ok ? p[0] : 0.f;
                    float v1 = ok ? p[1] : 0.f;
                    float v2 = ok ? p[2] : 0.f;
                    const float wv = wp[dh * KK + dw];
                    a0 = fmaf(v0, wv, a0);
                    a1 = fmaf(v1, wv, a1);
                    a2 = fmaf(v2, wv, a2);
                }
            }
            float* o = out + (((long)(n * HH + hh)) * WW + w) * CC;
            o[0] = a0; o[1] = a1; o[2] = a2;
        }
    }
}

extern "C" void kernel_launch(void* const* d_in, const int* in_sizes, int n_in,
                              void* d_out, int out_size, void* d_ws, size_t ws_size,
                              hipStream_t stream) {
    const float* in = (const float*)d_in[0];   // (8,512,512,3) f32
    const float* wt = (const float*)d_in[1];   // (8,512,512,25) f32
    float* out = (float*)d_out;                // (8,512,512,3) f32

    conv_local_kernel<<<NBLOCKS, 64, 0, stream>>>(in, wt, out);
}

// Round 8
// 58.384 us; speedup vs baseline: 2.0169x; 1.0098x over previous
//
#include <hip/hip_runtime.h>

#define NN 8
#define HH 512
#define WW 512
#define CC 3
#define KK 5
#define PADP 2
#define WROWF (WW * CC)                 // 1536 floats per image row
#define NBLOCKS (NN * HH * WW / 128)    // 16384 blocks: 64 px wide x 2 rows

typedef float f4a __attribute__((ext_vector_type(4), aligned(4)));

struct Row { f4a L0, L1, L2, L3; };     // 15-float window f0..f14 (L3 overlaps at f11)

__device__ __forceinline__ void load_row(const float* rb, Row& r) {
    r.L0 = *(const f4a*)(rb);
    r.L1 = *(const f4a*)(rb + 4);
    r.L2 = *(const f4a*)(rb + 8);
    r.L3 = *(const f4a*)(rb + 11);
}

// taps: dw uses floats [3*dw .. 3*dw+2] of the window
__device__ __forceinline__ void fma_row(const Row& r, const float* wp,
                                        float& a0, float& a1, float& a2) {
    const float w0 = wp[0], w1 = wp[1], w2 = wp[2], w3 = wp[3], w4 = wp[4];
    a0 = fmaf(r.L0[0], w0, a0); a1 = fmaf(r.L0[1], w0, a1); a2 = fmaf(r.L0[2], w0, a2);
    a0 = fmaf(r.L0[3], w1, a0); a1 = fmaf(r.L1[0], w1, a1); a2 = fmaf(r.L1[1], w1, a2);
    a0 = fmaf(r.L1[2], w2, a0); a1 = fmaf(r.L1[3], w2, a1); a2 = fmaf(r.L2[0], w2, a2);
    a0 = fmaf(r.L2[1], w3, a0); a1 = fmaf(r.L2[2], w3, a1); a2 = fmaf(r.L2[3], w3, a2);
    a0 = fmaf(r.L3[1], w4, a0); a1 = fmaf(r.L3[2], w4, a1); a2 = fmaf(r.L3[3], w4, a2);
}

#define GLDS16(gp, lp) __builtin_amdgcn_global_load_lds( \
    (const __attribute__((address_space(1))) void*)(gp), \
    (__attribute__((address_space(3))) void*)(lp), 16, 0, 0)
#define GLDS4(gp, lp) __builtin_amdgcn_global_load_lds( \
    (const __attribute__((address_space(1))) void*)(gp), \
    (__attribute__((address_space(3))) void*)(lp), 4, 0, 0)

__global__ __launch_bounds__(64, 3) void conv_local_kernel(
    const float* __restrict__ in,   // (N,H,W,C)
    const float* __restrict__ wt,   // (N,H,W,25)
    float* __restrict__ out)        // (N,H,W,C)
{
    __shared__ float w_lds[2 * 64 * KK * KK];   // 3200 f = 12.8 KB

    const int lane = threadIdx.x;
    // bijective XCD swizzle: 16384 = 8 x 2048; each XCD streams one image linearly
    const int b    = ((blockIdx.x & 7) << 11) | (blockIdx.x >> 3);
    const int wseg = b & 7;
    const int hp   = (b >> 3) & 255;
    const int n    = b >> 11;
    const int w0   = wseg << 6;                 // 0..448
    const int h0   = hp << 1;                   // 0..510

    const long pix0 = ((long)(n * HH + h0)) * WW + w0;   // row h0, col w0
    const long pix1 = pix0 + WW;                          // row h0+1
    const float* inb = in + (size_t)n * (HH * WW * CC);

    // ---- stage weights for both output rows: async global->LDS, issued first (HBM) ----
    {
        const char* s0 = (const char*)(wt + pix0 * (KK * KK));
        const char* s1 = (const char*)(wt + pix1 * (KK * KK));
#pragma unroll
        for (int it = 0; it < 6; ++it)
            GLDS16(s0 + it * 1024 + lane * 16, &w_lds[it * 256]);
        GLDS4(s0 + 6144 + lane * 4, &w_lds[1536]);
#pragma unroll
        for (int it = 0; it < 6; ++it)
            GLDS16(s1 + it * 1024 + lane * 16, &w_lds[1600 + it * 256]);
        GLDS4(s1 + 6144 + lane * 4, &w_lds[1600 + 1536]);
    }

    const float* wp0 = &w_lds[lane * (KK * KK)];          // px row h0 weights
    const float* wp1 = &w_lds[1600 + lane * (KK * KK)];   // px row h0+1 weights

    const bool fast = (w0 != 0) && (w0 != WW - 64) && (h0 >= PADP) && (h0 <= HH - 4);

    if (fast) {
        // 6 input rows gh = h0-2 .. h0+3, ALL loaded upfront: their L1/L2 latency
        // overlaps the weight drain; zero mid-compute memory stalls.
        const float* rb = inb + ((long)(h0 - PADP) * WW + (w0 + lane - PADP)) * CC;
        Row R0, R1, R2, R3, R4, R5;
        load_row(rb,             R0);
        load_row(rb + 1 * WROWF, R1);
        load_row(rb + 2 * WROWF, R2);
        load_row(rb + 3 * WROWF, R3);
        load_row(rb + 4 * WROWF, R4);
        load_row(rb + 5 * WROWF, R5);
        // drain global_load_lds before ds_reads (dependency not register-tracked)
        asm volatile("s_waitcnt vmcnt(0)" ::: "memory");
        __builtin_amdgcn_sched_barrier(0);

        float a0 = 0.f, a1 = 0.f, a2 = 0.f;   // acc for px (h0, w)
        float c0 = 0.f, c1 = 0.f, c2 = 0.f;   // acc for px (h0+1, w)

        fma_row(R0, wp0 + 0,  a0, a1, a2);
        fma_row(R1, wp0 + 5,  a0, a1, a2);
        fma_row(R1, wp1 + 0,  c0, c1, c2);
        fma_row(R2, wp0 + 10, a0, a1, a2);
        fma_row(R2, wp1 + 5,  c0, c1, c2);
        fma_row(R3, wp0 + 15, a0, a1, a2);
        fma_row(R3, wp1 + 10, c0, c1, c2);
        fma_row(R4, wp0 + 20, a0, a1, a2);
        fma_row(R4, wp1 + 15, c0, c1, c2);
        fma_row(R5, wp1 + 20, c0, c1, c2);

        float* o0 = out + (pix0 + lane) * CC;
        o0[0] = a0; o0[1] = a1; o0[2] = a2;
        float* o1 = out + (pix1 + lane) * CC;
        o1[0] = c0; o1[1] = c1; o1[2] = c2;
    } else {
        asm volatile("s_waitcnt vmcnt(0)" ::: "memory");
        __builtin_amdgcn_sched_barrier(0);
        // border blocks: predicated scalar path (proven in R1), weights from LDS
#pragma unroll
        for (int px = 0; px < 2; ++px) {
            const int hh = h0 + px;
            const int w  = w0 + lane;
            const float* wp = px ? wp1 : wp0;
            float a0 = 0.f, a1 = 0.f, a2 = 0.f;
#pragma unroll
            for (int dh = 0; dh < KK; ++dh) {
                const int ih = hh + dh - PADP;
                const bool rok = ((unsigned)ih < (unsigned)HH);
#pragma unroll
                for (int dw = 0; dw < KK; ++dw) {
                    const int iw = w + dw - PADP;
                    const bool ok = rok && ((unsigned)iw < (unsigned)WW);
                    const float* p = inb + ((long)(ih * WW + iw)) * CC;
                    float v0 = ok ? p[0] : 0.f;
                    float v1 = ok ? p[1] : 0.f;
                    float v2 = ok ? p[2] : 0.f;
                    const float wv = wp[dh * KK + dw];
                    a0 = fmaf(v0, wv, a0);
                    a1 = fmaf(v1, wv, a1);
                    a2 = fmaf(v2, wv, a2);
                }
            }
            float* o = out + (((long)(n * HH + hh)) * WW + w) * CC;
            o[0] = a0; o[1] = a1; o[2] = a2;
        }
    }
}

extern "C" void kernel_launch(void* const* d_in, const int* in_sizes, int n_in,
                              void* d_out, int out_size, void* d_ws, size_t ws_size,
                              hipStream_t stream) {
    const float* in = (const float*)d_in[0];   // (8,512,512,3) f32
    const float* wt = (const float*)d_in[1];   // (8,512,512,25) f32
    float* out = (float*)d_out;                // (8,512,512,3) f32

    conv_local_kernel<<<NBLOCKS, 64, 0, stream>>>(in, wt, out);
}